// Round 2
// baseline (5898.523 us; speedup 1.0000x reference)
//
#include <hip/hip_runtime.h>
#include <cstdint>
#include <cstddef>

// Problem constants
// x: (8, 64, 70, 70) fp32; convs 7x7 VALID -> (8, oc, 64, 64)
// theta: oc 0..99, phi: oc 100..199 (pooled), g: oc 200..399 (pooled)
// N = 4096, M = 1024
#define BATCH 8
#define CIN 64
#define HIN 70
#define HOUT 64
#define NPIX 4096
#define MPIX 1024
#define TN 16

// ---------------------------------------------------------------------------
// Conv kernel: block = (b, 4 output rows, 16 output channels), 256 threads
// thread = (ty in 0..3 row, ox in 0..63 col), 16 acc per thread (one per oc).
// Weights fetched with block-uniform addressing -> scalar loads (SGPR).
// ---------------------------------------------------------------------------
__global__ __launch_bounds__(256) void conv7_kernel(
    const float* __restrict__ x,
    const float* __restrict__ tw, const float* __restrict__ tb,
    const float* __restrict__ pw, const float* __restrict__ pb,
    const float* __restrict__ gw, const float* __restrict__ gb,
    float* __restrict__ conv_out) {
  __shared__ float sIn[8][10][72];  // 8 input ch, 10 rows, 70(+2 pad) cols

  const int bx = blockIdx.x;      // 0..127 = b*16 + oyg
  const int b = bx >> 4;
  const int oyg = bx & 15;        // group of 4 output rows
  const int oc0 = blockIdx.y * 16;

  const int t = threadIdx.x;
  const int ty = t >> 6;          // 0..3
  const int ox = t & 63;          // 0..63
  const int oy = oyg * 4 + ty;

  // Uniform per-oc weight base pointers + biases (SGPRs)
  const float* wp[16];
  float bias[16];
#pragma unroll
  for (int j = 0; j < 16; ++j) {
    int oc = oc0 + j;
    if (oc < 100) {
      wp[j] = tw + (size_t)oc * (CIN * 49);
      bias[j] = tb[oc];
    } else if (oc < 200) {
      wp[j] = pw + (size_t)(oc - 100) * (CIN * 49);
      bias[j] = pb[oc - 100];
    } else {
      wp[j] = gw + (size_t)(oc - 200) * (CIN * 49);
      bias[j] = gb[oc - 200];
    }
  }

  float acc[16];
#pragma unroll
  for (int j = 0; j < 16; ++j) acc[j] = 0.0f;

  for (int c0 = 0; c0 < CIN; c0 += 8) {
    __syncthreads();
    // stage 8 channels x 10 rows x 70 cols
    for (int i = t; i < 8 * 10 * 70; i += 256) {
      int c = i / 700;
      int rem = i - c * 700;
      int r = rem / 70;
      int col = rem - r * 70;
      sIn[c][r][col] =
          x[(((size_t)(b * CIN + c0 + c)) * HIN + (oyg * 4 + r)) * HIN + col];
    }
    __syncthreads();

    for (int c = 0; c < 8; ++c) {
      // load 7x7 window into registers (reused across 16 oc)
      float v[49];
#pragma unroll
      for (int ky = 0; ky < 7; ++ky)
#pragma unroll
        for (int kx = 0; kx < 7; ++kx)
          v[ky * 7 + kx] = sIn[c][ty + ky][ox + kx];

#pragma unroll
      for (int j = 0; j < 16; ++j) {
        const float* w = wp[j] + (size_t)(c0 + c) * 49;  // uniform -> s_load
#pragma unroll
        for (int k = 0; k < 49; ++k) acc[j] = fmaf(w[k], v[k], acc[j]);
      }
    }
  }

  float* outp = conv_out + ((size_t)(b * 400 + oc0)) * NPIX + (oy * HOUT + ox);
#pragma unroll
  for (int j = 0; j < 16; ++j) outp[(size_t)j * NPIX] = acc[j] + bias[j];
}

// ---------------------------------------------------------------------------
// Maxpool 2x2 for phi (ch 100..199) -> phi_p[b][c][m]  (c-major)
//                and g (ch 200..399) -> gT[b][m][c]    (m-major, for float4)
// ---------------------------------------------------------------------------
__global__ __launch_bounds__(256) void pool_kernel(
    const float* __restrict__ conv_out,
    float* __restrict__ phi_p, float* __restrict__ gT) {
  int idx = blockIdx.x * 256 + threadIdx.x;  // 8*300*1024 total
  if (idx >= BATCH * 300 * MPIX) return;
  int m = idx & 1023;
  int c = (idx >> 10) % 300;
  int b = idx / (300 * MPIX);
  int my = m >> 5, mx = m & 31;
  int ch = (c < 100) ? (100 + c) : (200 + (c - 100));
  const float* base = conv_out + ((size_t)(b * 400 + ch)) * NPIX;
  int y = my * 2, xx = mx * 2;
  float v0 = base[y * HOUT + xx];
  float v1 = base[y * HOUT + xx + 1];
  float v2 = base[(y + 1) * HOUT + xx];
  float v3 = base[(y + 1) * HOUT + xx + 1];
  float v = fmaxf(fmaxf(v0, v1), fmaxf(v2, v3));
  if (c < 100)
    phi_p[((size_t)(b * 100 + c) << 10) + m] = v;
  else
    gT[(((size_t)b << 10) + m) * 200 + (c - 100)] = v;
}

// ---------------------------------------------------------------------------
// Fused attention: block = (b, 16-row n-tile).
// Phase A: logits L[16][1024] in LDS (padded to 1028)
// Phase B: wave-parallel softmax (unnormalized exp + 1/sum)
// Phase C: out[c, n] = inv_sum[n] * sum_m gT[m][c] * P[n][m]
// ---------------------------------------------------------------------------
__global__ __launch_bounds__(256) void attn_kernel(
    const float* __restrict__ conv_out,   // theta = channels 0..99
    const float* __restrict__ phi_p,      // [b][100][1024]
    const float* __restrict__ gT,         // [b][1024][200]
    float* __restrict__ out) {            // [b][200][4096]
  __shared__ __align__(16) float sL[TN][1028];
  __shared__ float sTheta[100][TN];
  __shared__ float sInv[TN];

  const int bx = blockIdx.x;        // 0..2047
  const int b = bx >> 8;
  const int tile = bx & 255;
  const int n0 = tile * TN;
  const int t = threadIdx.x;

  // load theta tile: [100][16]
  for (int i = t; i < 100 * TN; i += 256) {
    int c = i / TN;
    int nn = i - c * TN;
    sTheta[c][nn] = conv_out[(((size_t)(b * 400 + c)) << 12) + n0 + nn];
  }
  __syncthreads();

  // Phase A: each thread owns 4 consecutive m for all 16 n
  {
    float acc[TN][4];
#pragma unroll
    for (int nn = 0; nn < TN; ++nn) {
      acc[nn][0] = 0.f; acc[nn][1] = 0.f; acc[nn][2] = 0.f; acc[nn][3] = 0.f;
    }
    const int m4 = t * 4;
    const float* pp = phi_p + ((size_t)b * 100) * MPIX + m4;
    for (int c = 0; c < 100; ++c) {
      float4 ph = *reinterpret_cast<const float4*>(pp);
      pp += MPIX;
#pragma unroll
      for (int nn = 0; nn < TN; ++nn) {
        float th = sTheta[c][nn];
        acc[nn][0] = fmaf(th, ph.x, acc[nn][0]);
        acc[nn][1] = fmaf(th, ph.y, acc[nn][1]);
        acc[nn][2] = fmaf(th, ph.z, acc[nn][2]);
        acc[nn][3] = fmaf(th, ph.w, acc[nn][3]);
      }
    }
#pragma unroll
    for (int nn = 0; nn < TN; ++nn) {
      *reinterpret_cast<float4*>(&sL[nn][m4]) =
          make_float4(acc[nn][0], acc[nn][1], acc[nn][2], acc[nn][3]);
    }
  }
  __syncthreads();

  // Phase B: softmax per row; wave w handles rows w, w+4, w+8, w+12
  {
    const int wave = t >> 6;
    const int lane = t & 63;
#pragma unroll
    for (int rr = 0; rr < TN / 4; ++rr) {
      const int nn = wave + rr * 4;
      float vals[16];
      float mx = -3.0e38f;
#pragma unroll
      for (int i = 0; i < 16; ++i) {
        vals[i] = sL[nn][lane + (i << 6)];
        mx = fmaxf(mx, vals[i]);
      }
#pragma unroll
      for (int s = 1; s < 64; s <<= 1) mx = fmaxf(mx, __shfl_xor(mx, s));
      float sum = 0.f;
#pragma unroll
      for (int i = 0; i < 16; ++i) {
        float e = __expf(vals[i] - mx);
        vals[i] = e;
        sum += e;
      }
#pragma unroll
      for (int s = 1; s < 64; s <<= 1) sum += __shfl_xor(sum, s);
#pragma unroll
      for (int i = 0; i < 16; ++i) sL[nn][lane + (i << 6)] = vals[i];
      if (lane == 0) sInv[nn] = 1.0f / sum;
    }
  }
  __syncthreads();

  // Phase C: thread t -> cg = t>>2 (4 channels), ng = t&3 (+4j rows)
  {
    const int cg = t >> 2;  // 0..63, active < 50
    const int ng = t & 3;
    if (cg < 50) {
      float a2[4][4];
#pragma unroll
      for (int jc = 0; jc < 4; ++jc)
#pragma unroll
        for (int jn = 0; jn < 4; ++jn) a2[jc][jn] = 0.f;

      const float* gp = gT + ((size_t)b << 10) * 200 + cg * 4;
      for (int m = 0; m < MPIX; ++m) {
        float4 g4 = *reinterpret_cast<const float4*>(gp + (size_t)m * 200);
#pragma unroll
        for (int jn = 0; jn < 4; ++jn) {
          float p = sL[ng + (jn << 2)][m];
          a2[0][jn] = fmaf(g4.x, p, a2[0][jn]);
          a2[1][jn] = fmaf(g4.y, p, a2[1][jn]);
          a2[2][jn] = fmaf(g4.z, p, a2[2][jn]);
          a2[3][jn] = fmaf(g4.w, p, a2[3][jn]);
        }
      }
#pragma unroll
      for (int jc = 0; jc < 4; ++jc) {
#pragma unroll
        for (int jn = 0; jn < 4; ++jn) {
          int c = cg * 4 + jc;
          int nl = ng + (jn << 2);
          out[(((size_t)(b * 200 + c)) << 12) + n0 + nl] = a2[jc][jn] * sInv[nl];
        }
      }
    }
  }
}

// ---------------------------------------------------------------------------
extern "C" void kernel_launch(void* const* d_in, const int* in_sizes, int n_in,
                              void* d_out, int out_size, void* d_ws,
                              size_t ws_size, hipStream_t stream) {
  const float* x  = (const float*)d_in[0];
  const float* tw = (const float*)d_in[1];
  const float* tb = (const float*)d_in[2];
  const float* pw = (const float*)d_in[3];
  const float* pb = (const float*)d_in[4];
  const float* gw = (const float*)d_in[5];
  const float* gb = (const float*)d_in[6];
  float* out = (float*)d_out;

  float* ws = (float*)d_ws;
  float* conv_out = ws;                        // 8*400*4096 = 13,107,200 f
  float* phi_p = ws + 13107200;                // 8*100*1024 =    819,200 f
  float* gT    = ws + 13107200 + 819200;       // 8*1024*200 =  1,638,400 f
                                               // total 62.3 MB

  conv7_kernel<<<dim3(128, 25), 256, 0, stream>>>(x, tw, tb, pw, pb, gw, gb,
                                                  conv_out);
  pool_kernel<<<9600, 256, 0, stream>>>(conv_out, phi_p, gT);
  attn_kernel<<<2048, 256, 0, stream>>>(conv_out, phi_p, gT, out);
}

// Round 3
// 749.334 us; speedup vs baseline: 7.8717x; 7.8717x over previous
//
#include <hip/hip_runtime.h>
#include <cstdint>
#include <cstddef>

#define BATCH 8
#define CIN 64
#define HIN 70
#define HOUT 64
#define NPIX 4096
#define MPIX 1024
#define TN 16

typedef __attribute__((ext_vector_type(8))) short short8;
typedef __attribute__((ext_vector_type(4))) float f32x4;
typedef __attribute__((ext_vector_type(4))) unsigned int uint4v;

__device__ __forceinline__ unsigned short f2bf_rne(float f) {
  unsigned int u = __builtin_bit_cast(unsigned int, f);
  unsigned int r = (u + 0x7FFFu + ((u >> 16) & 1u)) >> 16;
  return (unsigned short)r;
}

// ---------------------------------------------------------------------------
// prep_x: x [8][64][70][70] f32 -> xTi [8][70][70][128] ushort (hi/lo pairs)
// block = (b, r); LDS transpose for coalescing both sides.
// ---------------------------------------------------------------------------
__global__ __launch_bounds__(256) void prep_x(const float* __restrict__ x,
                                              unsigned int* __restrict__ xTi) {
  __shared__ float tile[64][71];
  const int blk = blockIdx.x;  // 0..559
  const int b = blk / 70;
  const int r = blk - b * 70;
  const int t = threadIdx.x;
  for (int i = t; i < 64 * 70; i += 256) {
    int ci = i / 70;
    int c = i - ci * 70;
    tile[ci][c] = x[(((size_t)(b * 64 + ci)) * 70 + r) * 70 + c];
  }
  __syncthreads();
  // out dword index: ((b*70+r)*70+c)*64 + ci
  for (int i = t; i < 70 * 64; i += 256) {
    int c = i >> 6;
    int ci = i & 63;
    float a = tile[ci][c];
    unsigned short hi = f2bf_rne(a);
    float hif = __builtin_bit_cast(float, ((unsigned int)hi) << 16);
    unsigned short lo = f2bf_rne(a - hif);
    xTi[(((size_t)(b * 70 + r)) * 70 + c) * 64 + ci] =
        (unsigned int)hi | (((unsigned int)lo) << 16);
  }
}

// ---------------------------------------------------------------------------
// prep_w: weights -> wTi [49][512][128] ushort (hi/lo pairs).
// OC 0..99 = theta, 100..199 = phi, 200..255 = pad0, 256..455 = g, rest pad0
// ---------------------------------------------------------------------------
__global__ __launch_bounds__(256) void prep_w(
    const float* __restrict__ tw, const float* __restrict__ pw,
    const float* __restrict__ gw, unsigned int* __restrict__ wTi) {
  int gid = blockIdx.x * 256 + threadIdx.x;  // 49*512*64 dwords
  if (gid >= 49 * 512 * 64) return;
  int ci = gid & 63;
  int OC = (gid >> 6) & 511;
  int s = gid >> 15;  // 0..48
  float v = 0.0f;
  if (OC < 256) {
    if (OC < 100) v = tw[((size_t)(OC * 64 + ci)) * 49 + s];
    else if (OC < 200) v = pw[((size_t)((OC - 100) * 64 + ci)) * 49 + s];
  } else {
    int oc = OC - 256;
    if (oc < 200) v = gw[((size_t)(oc * 64 + ci)) * 49 + s];
  }
  unsigned short hi = f2bf_rne(v);
  float hif = __builtin_bit_cast(float, ((unsigned int)hi) << 16);
  unsigned short lo = f2bf_rne(v - hif);
  wTi[gid] = (unsigned int)hi | (((unsigned int)lo) << 16);
}

__global__ __launch_bounds__(256) void prep_bias(
    const float* __restrict__ tb, const float* __restrict__ pb,
    const float* __restrict__ gb, float* __restrict__ biasPad) {
  int i = blockIdx.x * 256 + threadIdx.x;
  if (i >= 512) return;
  float v = 0.0f;
  if (i < 100) v = tb[i];
  else if (i < 200) v = pb[i - 100];
  else if (i >= 256 && i < 456) v = gb[i - 256];
  biasPad[i] = v;
}

// ---------------------------------------------------------------------------
// convmfma: dual-bf16 implicit-GEMM conv, fused bias + 2x2 maxpool for phi/g.
// grid (128, 8): x = b*16+ptile, y = octile (0..3 theta/phi, 4..7 g)
// block tile: 64 oc x (4 rows x 64 cols). 4 waves: wave = (h pixhalf, ocq)
// LDS: X chunk [10][70][16ci*2parts] swizzled (44800 B) + W dbuf 2x4096 B
// ---------------------------------------------------------------------------
__global__ __launch_bounds__(256) void convmfma_kernel(
    const unsigned short* __restrict__ xTi,  // [8][70][70][128]
    const unsigned short* __restrict__ wTi,  // [49][512][128]
    const float* __restrict__ biasPad,       // [512]
    float* __restrict__ theta_out,           // [8][100][4096]
    float* __restrict__ phi_p,               // [8][100][1024]
    float* __restrict__ gT) {                // [8][1024][200]
  __shared__ __align__(16) char smem[44800 + 8192];
  const int LDSW = 44800;

  const int gx = blockIdx.x;
  const int b = gx >> 4;
  const int ptile = gx & 15;
  const int oy0 = ptile * 4;
  const int oc0 = blockIdx.y << 6;  // 0..448

  const int t = threadIdx.x;
  const int wv = t >> 6;
  const int l = t & 63;
  const int h = wv >> 1;    // pixel half (row pair)
  const int ocq = wv & 1;   // oc half (32)
  const int lm = l & 15;
  const int lg = l >> 4;

  const int keyA = ((lm >> 1) & 3) << 4;
  const int laneA = (ocq << 11) + (lm << 6) + ((lg << 4) ^ keyA);
  const int rowbase = 2 * h;

  // staging ids
  const int oc_t = t >> 2;  // 0..63
  const int q = t & 3;

  f32x4 acc[2][8];
#pragma unroll
  for (int o = 0; o < 2; ++o)
#pragma unroll
    for (int f = 0; f < 8; ++f) acc[o][f] = (f32x4)0.0f;

  for (int chunk = 0; chunk < 4; ++chunk) {
    __syncthreads();  // prior chunk compute done
    // ---- stage X chunk: [10][70] lines of 64B (16 ci hi/lo interleaved)
    for (int i = t; i < 2800; i += 256) {
      int idx70 = i >> 2;
      int s16 = i & 3;
      int rr = idx70 / 70;
      int cc = idx70 - rr * 70;
      const unsigned short* src =
          xTi + ((((size_t)(b * 70 + oy0 + rr)) * 70 + cc) << 7) +
          (chunk << 5) + (s16 << 3);
      short8 v = *(const short8*)src;
      int dst = (idx70 << 6) + ((s16 << 4) ^ (((cc >> 1) & 3) << 4));
      *(short8*)(smem + dst) = v;
    }
    // ---- W prologue
    const unsigned short* wsrc0 =
        wTi + (((size_t)(0 * 512) + oc0 + oc_t) << 7) + (chunk << 5) + (q << 3);
    short8 wreg = *(const short8*)wsrc0;
    int buf = 0;
    int wdstLane = (oc_t << 6) + ((q << 4) ^ (((oc_t >> 1) & 3) << 4));

    for (int ky = 0; ky < 7; ++ky) {
      for (int kx = 0; kx < 7; ++kx) {
        int s = ky * 7 + kx;
        __syncthreads();  // X visible (first slice); prev compute done
        *(short8*)(smem + LDSW + (buf << 12) + wdstLane) = wreg;
        short8 wnext = wreg;
        if (s < 48) {
          const unsigned short* wsrc =
              wTi + ((((size_t)(s + 1)) * 512 + oc0 + oc_t) << 7) +
              (chunk << 5) + (q << 3);
          wnext = *(const short8*)wsrc;
        }
        __syncthreads();  // wbuf ready

        // ---- compute slice
        int klx = kx + lm;
        int key = ((klx >> 1) & 3) << 4;
        int kk = (lg << 4) ^ key;
        const char* bbase = smem + (rowbase + ky) * 4480 + klx * 64 + kk;
        const char* abase = smem + LDSW + (buf << 12) + laneA;
        short8 a0 = *(const short8*)(abase);
        short8 a1 = *(const short8*)(abase + 1024);
#pragma unroll
        for (int f = 0; f < 8; ++f) {
          const int off = (f >> 2) * 4480 + (f & 3) * 1024;
          uint4v bu = *(const uint4v*)(bbase + off);
          short8 b1 = __builtin_bit_cast(short8, bu);
          acc[0][f] = __builtin_amdgcn_mfma_f32_16x16x32_bf16(a0, b1,
                                                              acc[0][f], 0, 0, 0);
          acc[1][f] = __builtin_amdgcn_mfma_f32_16x16x32_bf16(a1, b1,
                                                              acc[1][f], 0, 0, 0);
          uint4v bs;
          bs.x = (bu.x >> 16) | (bu.x << 16);
          bs.y = (bu.y >> 16) | (bu.y << 16);
          bs.z = (bu.z >> 16) | (bu.z << 16);
          bs.w = (bu.w >> 16) | (bu.w << 16);
          short8 b2 = __builtin_bit_cast(short8, bs);
          acc[0][f] = __builtin_amdgcn_mfma_f32_16x16x32_bf16(a0, b2,
                                                              acc[0][f], 0, 0, 0);
          acc[1][f] = __builtin_amdgcn_mfma_f32_16x16x32_bf16(a1, b2,
                                                              acc[1][f], 0, 0, 0);
        }
        wreg = wnext;
        buf ^= 1;
      }
    }
  }

  // ---- epilogue: bias, theta full-res write, phi/g fused 2x2 maxpool
  float bia[2][4];
#pragma unroll
  for (int o = 0; o < 2; ++o)
#pragma unroll
    for (int r = 0; r < 4; ++r)
      bia[o][r] = biasPad[oc0 + (ocq << 5) + o * 16 + lg * 4 + r];

  const bool thetaMode = (oc0 < 256);

  if (thetaMode) {
#pragma unroll
    for (int o = 0; o < 2; ++o)
#pragma unroll
      for (int f = 0; f < 8; ++f)
#pragma unroll
        for (int r = 0; r < 4; ++r) {
          int ch = oc0 + (ocq << 5) + o * 16 + lg * 4 + r;
          if (ch < 100) {
            int row = oy0 + 2 * h + (f >> 2);
            int col = ((f & 3) << 4) + lm;
            theta_out[(((size_t)(b * 100 + ch)) << 12) + row * 64 + col] =
                acc[o][f][r] + bia[o][r];
          }
        }
  }

#pragma unroll
  for (int o = 0; o < 2; ++o)
#pragma unroll
    for (int f = 0; f < 4; ++f)
#pragma unroll
      for (int r = 0; r < 4; ++r) {
        float v = fmaxf(acc[o][f][r], acc[o][f + 4][r]) + bia[o][r];
        float vn = fmaxf(v, __shfl_xor(v, 1));
        int ch = oc0 + (ocq << 5) + o * 16 + lg * 4 + r;
        if (!(lm & 1)) {
          int prow = (oy0 >> 1) + h;
          int mcol = (f << 3) + (lm >> 1);
          int m = (prow << 5) + mcol;
          if (thetaMode) {
            if (ch >= 100 && ch < 200)
              phi_p[(((size_t)(b * 100 + ch - 100)) << 10) + m] = vn;
          } else {
            int cg = ch - 256;
            if (cg < 200) gT[(((size_t)(b << 10) + m)) * 200 + cg] = vn;
          }
        }
      }
}

// ---------------------------------------------------------------------------
// Fused attention (unchanged structure from round 2; theta buffer is 100-ch)
// ---------------------------------------------------------------------------
__global__ __launch_bounds__(256) void attn_kernel(
    const float* __restrict__ theta,      // [8][100][4096]
    const float* __restrict__ phi_p,      // [8][100][1024]
    const float* __restrict__ gT,         // [8][1024][200]
    float* __restrict__ out) {            // [8][200][4096]
  __shared__ __align__(16) float sL[TN][1028];
  __shared__ float sTheta[100][TN];
  __shared__ float sInv[TN];

  const int bx = blockIdx.x;        // 0..2047
  const int b = bx >> 8;
  const int tile = bx & 255;
  const int n0 = tile * TN;
  const int t = threadIdx.x;

  for (int i = t; i < 100 * TN; i += 256) {
    int c = i / TN;
    int nn = i - c * TN;
    sTheta[c][nn] = theta[(((size_t)(b * 100 + c)) << 12) + n0 + nn];
  }
  __syncthreads();

  {
    float acc[TN][4];
#pragma unroll
    for (int nn = 0; nn < TN; ++nn) {
      acc[nn][0] = 0.f; acc[nn][1] = 0.f; acc[nn][2] = 0.f; acc[nn][3] = 0.f;
    }
    const int m4 = t * 4;
    const float* pp = phi_p + ((size_t)b * 100) * MPIX + m4;
    for (int c = 0; c < 100; ++c) {
      float4 ph = *reinterpret_cast<const float4*>(pp);
      pp += MPIX;
#pragma unroll
      for (int nn = 0; nn < TN; ++nn) {
        float th = sTheta[c][nn];
        acc[nn][0] = fmaf(th, ph.x, acc[nn][0]);
        acc[nn][1] = fmaf(th, ph.y, acc[nn][1]);
        acc[nn][2] = fmaf(th, ph.z, acc[nn][2]);
        acc[nn][3] = fmaf(th, ph.w, acc[nn][3]);
      }
    }
#pragma unroll
    for (int nn = 0; nn < TN; ++nn) {
      *reinterpret_cast<float4*>(&sL[nn][m4]) =
          make_float4(acc[nn][0], acc[nn][1], acc[nn][2], acc[nn][3]);
    }
  }
  __syncthreads();

  {
    const int wave = t >> 6;
    const int lane = t & 63;
#pragma unroll
    for (int rr = 0; rr < TN / 4; ++rr) {
      const int nn = wave + rr * 4;
      float vals[16];
      float mx = -3.0e38f;
#pragma unroll
      for (int i = 0; i < 16; ++i) {
        vals[i] = sL[nn][lane + (i << 6)];
        mx = fmaxf(mx, vals[i]);
      }
#pragma unroll
      for (int s = 1; s < 64; s <<= 1) mx = fmaxf(mx, __shfl_xor(mx, s));
      float sum = 0.f;
#pragma unroll
      for (int i = 0; i < 16; ++i) {
        float e = __expf(vals[i] - mx);
        vals[i] = e;
        sum += e;
      }
#pragma unroll
      for (int s = 1; s < 64; s <<= 1) sum += __shfl_xor(sum, s);
#pragma unroll
      for (int i = 0; i < 16; ++i) sL[nn][lane + (i << 6)] = vals[i];
      if (lane == 0) sInv[nn] = 1.0f / sum;
    }
  }
  __syncthreads();

  {
    const int cg = t >> 2;
    const int ng = t & 3;
    if (cg < 50) {
      float a2[4][4];
#pragma unroll
      for (int jc = 0; jc < 4; ++jc)
#pragma unroll
        for (int jn = 0; jn < 4; ++jn) a2[jc][jn] = 0.f;

      const float* gp = gT + ((size_t)b << 10) * 200 + cg * 4;
      for (int m = 0; m < MPIX; ++m) {
        float4 g4 = *reinterpret_cast<const float4*>(gp + (size_t)m * 200);
#pragma unroll
        for (int jn = 0; jn < 4; ++jn) {
          float p = sL[ng + (jn << 2)][m];
          a2[0][jn] = fmaf(g4.x, p, a2[0][jn]);
          a2[1][jn] = fmaf(g4.y, p, a2[1][jn]);
          a2[2][jn] = fmaf(g4.z, p, a2[2][jn]);
          a2[3][jn] = fmaf(g4.w, p, a2[3][jn]);
        }
      }
#pragma unroll
      for (int jc = 0; jc < 4; ++jc) {
#pragma unroll
        for (int jn = 0; jn < 4; ++jn) {
          int c = cg * 4 + jc;
          int nl = ng + (jn << 2);
          out[(((size_t)(b * 200 + c)) << 12) + n0 + nl] = a2[jc][jn] * sInv[nl];
        }
      }
    }
  }
}

// ---------------------------------------------------------------------------
extern "C" void kernel_launch(void* const* d_in, const int* in_sizes, int n_in,
                              void* d_out, int out_size, void* d_ws,
                              size_t ws_size, hipStream_t stream) {
  const float* x  = (const float*)d_in[0];
  const float* tw = (const float*)d_in[1];
  const float* tb = (const float*)d_in[2];
  const float* pw = (const float*)d_in[3];
  const float* pb = (const float*)d_in[4];
  const float* gw = (const float*)d_in[5];
  const float* gb = (const float*)d_in[6];
  float* out = (float*)d_out;

  float* ws = (float*)d_ws;
  float* theta_out = ws;                         // 3,276,800 f
  float* phi_p = ws + 3276800;                   //   819,200 f
  float* gT    = ws + 4096000;                   // 1,638,400 f
  unsigned short* xTi = (unsigned short*)(ws + 5734400);   // 5,017,600 us
  unsigned short* wTi = (unsigned short*)(ws + 8243200);   // 3,211,264 us
  float* biasPad = ws + 9848832;                 // 512 f  (total 39.4 MB)

  prep_x<<<560, 256, 0, stream>>>(x, (unsigned int*)xTi);
  prep_w<<<(49 * 512 * 64 + 255) / 256, 256, 0, stream>>>(tw, pw, gw,
                                                          (unsigned int*)wTi);
  prep_bias<<<2, 256, 0, stream>>>(tb, pb, gb, biasPad);

  convmfma_kernel<<<dim3(128, 8), 256, 0, stream>>>(xTi, wTi, biasPad,
                                                    theta_out, phi_p, gT);
  attn_kernel<<<2048, 256, 0, stream>>>(theta_out, phi_p, gT, out);
}

// Round 5
// 543.587 us; speedup vs baseline: 10.8511x; 1.3785x over previous
//
#include <hip/hip_runtime.h>
#include <cstdint>
#include <cstddef>

#define BATCH 8
#define CIN 64
#define HIN 70
#define HOUT 64
#define NPIX 4096
#define MPIX 1024

typedef __attribute__((ext_vector_type(8))) short short8;
typedef __attribute__((ext_vector_type(4))) float f32x4;
typedef __attribute__((ext_vector_type(4))) unsigned int uint4v;

__device__ __forceinline__ unsigned short f2bf_rne(float f) {
  unsigned int u = __builtin_bit_cast(unsigned int, f);
  unsigned int r = (u + 0x7FFFu + ((u >> 16) & 1u)) >> 16;
  return (unsigned short)r;
}

// ---------------------------------------------------------------------------
// prep_x: x [8][64][70][70] f32 -> xTi [8][70][70][128] ushort (hi/lo pairs)
// ---------------------------------------------------------------------------
__global__ __launch_bounds__(256) void prep_x(const float* __restrict__ x,
                                              unsigned int* __restrict__ xTi) {
  __shared__ float tile[64][71];
  const int blk = blockIdx.x;  // 0..559
  const int b = blk / 70;
  const int r = blk - b * 70;
  const int t = threadIdx.x;
  for (int i = t; i < 64 * 70; i += 256) {
    int ci = i / 70;
    int c = i - ci * 70;
    tile[ci][c] = x[(((size_t)(b * 64 + ci)) * 70 + r) * 70 + c];
  }
  __syncthreads();
  for (int i = t; i < 70 * 64; i += 256) {
    int c = i >> 6;
    int ci = i & 63;
    float a = tile[ci][c];
    unsigned short hi = f2bf_rne(a);
    float hif = __builtin_bit_cast(float, ((unsigned int)hi) << 16);
    unsigned short lo = f2bf_rne(a - hif);
    xTi[(((size_t)(b * 70 + r)) * 70 + c) * 64 + ci] =
        (unsigned int)hi | (((unsigned int)lo) << 16);
  }
}

// ---------------------------------------------------------------------------
// prep_w: weights -> wTi [49][512][128] ushort (hi/lo pairs).
// ---------------------------------------------------------------------------
__global__ __launch_bounds__(256) void prep_w(
    const float* __restrict__ tw, const float* __restrict__ pw,
    const float* __restrict__ gw, unsigned int* __restrict__ wTi) {
  int gid = blockIdx.x * 256 + threadIdx.x;
  if (gid >= 49 * 512 * 64) return;
  int ci = gid & 63;
  int OC = (gid >> 6) & 511;
  int s = gid >> 15;
  float v = 0.0f;
  if (OC < 256) {
    if (OC < 100) v = tw[((size_t)(OC * 64 + ci)) * 49 + s];
    else if (OC < 200) v = pw[((size_t)((OC - 100) * 64 + ci)) * 49 + s];
  } else {
    int oc = OC - 256;
    if (oc < 200) v = gw[((size_t)(oc * 64 + ci)) * 49 + s];
  }
  unsigned short hi = f2bf_rne(v);
  float hif = __builtin_bit_cast(float, ((unsigned int)hi) << 16);
  unsigned short lo = f2bf_rne(v - hif);
  wTi[gid] = (unsigned int)hi | (((unsigned int)lo) << 16);
}

__global__ __launch_bounds__(256) void prep_bias(
    const float* __restrict__ tb, const float* __restrict__ pb,
    const float* __restrict__ gb, float* __restrict__ biasPad) {
  int i = blockIdx.x * 256 + threadIdx.x;
  if (i >= 512) return;
  float v = 0.0f;
  if (i < 100) v = tb[i];
  else if (i < 200) v = pb[i - 100];
  else if (i >= 256 && i < 456) v = gb[i - 256];
  biasPad[i] = v;
}

// ---------------------------------------------------------------------------
// zero_pads: zero the channel-pad regions of thd/phd (dw 100..127) and gP
// rows c=200..207 so MFMA K-padding contributes exactly 0.
// ---------------------------------------------------------------------------
__global__ __launch_bounds__(256) void zero_pads(
    unsigned int* __restrict__ thd_dw, unsigned int* __restrict__ phd_dw,
    unsigned int* __restrict__ g_dw) {
  int i = blockIdx.x * 256 + threadIdx.x;
  if (i < 917504) {
    int n = i / 28;
    int dw = 100 + (i - n * 28);
    thd_dw[((size_t)n << 7) + dw] = 0;
  } else if (i < 917504 + 229376) {
    int j = i - 917504;
    int m = j / 28;
    int dw = 100 + (j - m * 28);
    phd_dw[((size_t)m << 7) + dw] = 0;
  } else if (i < 917504 + 229376 + 32768) {
    int j = i - (917504 + 229376);
    int b = j >> 12;
    int off = j & 4095;
    g_dw[(size_t)b * 106496 + 102400 + off] = 0;
  }
}

// ---------------------------------------------------------------------------
// convmfma: dual-bf16 implicit-GEMM conv, epilogue emits attn-ready buffers:
//   thd [8][4096 n][128 dw]  theta dual-bf16
//   phd [8][1024 m][128 dw]  pooled phi dual-bf16
//   gP  [8][208 c][1024 m]   pooled g single-bf16
// ---------------------------------------------------------------------------
__global__ __launch_bounds__(256) void convmfma_kernel(
    const unsigned short* __restrict__ xTi,
    const unsigned short* __restrict__ wTi,
    const float* __restrict__ biasPad,
    unsigned int* __restrict__ thd_dw,
    unsigned int* __restrict__ phd_dw,
    unsigned short* __restrict__ gP) {
  __shared__ __align__(16) char smem[44800 + 8192];
  const int LDSW = 44800;

  const int gx = blockIdx.x;
  const int b = gx >> 4;
  const int ptile = gx & 15;
  const int oy0 = ptile * 4;
  const int oc0 = blockIdx.y << 6;

  const int t = threadIdx.x;
  const int wv = t >> 6;
  const int l = t & 63;
  const int h = wv >> 1;
  const int ocq = wv & 1;
  const int lm = l & 15;
  const int lg = l >> 4;

  const int keyA = ((lm >> 1) & 3) << 4;
  const int laneA = (ocq << 11) + (lm << 6) + ((lg << 4) ^ keyA);
  const int rowbase = 2 * h;

  const int oc_t = t >> 2;
  const int q = t & 3;

  f32x4 acc[2][8];
#pragma unroll
  for (int o = 0; o < 2; ++o)
#pragma unroll
    for (int f = 0; f < 8; ++f) acc[o][f] = (f32x4)0.0f;

  for (int chunk = 0; chunk < 4; ++chunk) {
    __syncthreads();
    for (int i = t; i < 2800; i += 256) {
      int idx70 = i >> 2;
      int s16 = i & 3;
      int rr = idx70 / 70;
      int cc = idx70 - rr * 70;
      const unsigned short* src =
          xTi + ((((size_t)(b * 70 + oy0 + rr)) * 70 + cc) << 7) +
          (chunk << 5) + (s16 << 3);
      short8 v = *(const short8*)src;
      int dst = (idx70 << 6) + ((s16 << 4) ^ (((cc >> 1) & 3) << 4));
      *(short8*)(smem + dst) = v;
    }
    const unsigned short* wsrc0 =
        wTi + (((size_t)(0 * 512) + oc0 + oc_t) << 7) + (chunk << 5) + (q << 3);
    short8 wreg = *(const short8*)wsrc0;
    int buf = 0;
    int wdstLane = (oc_t << 6) + ((q << 4) ^ (((oc_t >> 1) & 3) << 4));

    for (int ky = 0; ky < 7; ++ky) {
      for (int kx = 0; kx < 7; ++kx) {
        int s = ky * 7 + kx;
        __syncthreads();
        *(short8*)(smem + LDSW + (buf << 12) + wdstLane) = wreg;
        short8 wnext = wreg;
        if (s < 48) {
          const unsigned short* wsrc =
              wTi + ((((size_t)(s + 1)) * 512 + oc0 + oc_t) << 7) +
              (chunk << 5) + (q << 3);
          wnext = *(const short8*)wsrc;
        }
        __syncthreads();

        int klx = kx + lm;
        int key = ((klx >> 1) & 3) << 4;
        int kk = (lg << 4) ^ key;
        const char* bbase = smem + (rowbase + ky) * 4480 + klx * 64 + kk;
        const char* abase = smem + LDSW + (buf << 12) + laneA;
        short8 a0 = *(const short8*)(abase);
        short8 a1 = *(const short8*)(abase + 1024);
#pragma unroll
        for (int f = 0; f < 8; ++f) {
          const int off = (f >> 2) * 4480 + (f & 3) * 1024;
          uint4v bu = *(const uint4v*)(bbase + off);
          short8 b1 = __builtin_bit_cast(short8, bu);
          acc[0][f] = __builtin_amdgcn_mfma_f32_16x16x32_bf16(a0, b1,
                                                              acc[0][f], 0, 0, 0);
          acc[1][f] = __builtin_amdgcn_mfma_f32_16x16x32_bf16(a1, b1,
                                                              acc[1][f], 0, 0, 0);
          uint4v bs;
          bs.x = (bu.x >> 16) | (bu.x << 16);
          bs.y = (bu.y >> 16) | (bu.y << 16);
          bs.z = (bu.z >> 16) | (bu.z << 16);
          bs.w = (bu.w >> 16) | (bu.w << 16);
          short8 b2 = __builtin_bit_cast(short8, bs);
          acc[0][f] = __builtin_amdgcn_mfma_f32_16x16x32_bf16(a0, b2,
                                                              acc[0][f], 0, 0, 0);
          acc[1][f] = __builtin_amdgcn_mfma_f32_16x16x32_bf16(a1, b2,
                                                              acc[1][f], 0, 0, 0);
        }
        wreg = wnext;
        buf ^= 1;
      }
    }
  }

  float bia[2][4];
#pragma unroll
  for (int o = 0; o < 2; ++o)
#pragma unroll
    for (int r = 0; r < 4; ++r)
      bia[o][r] = biasPad[oc0 + (ocq << 5) + o * 16 + lg * 4 + r];

  const bool thetaMode = (oc0 < 256);

  if (thetaMode) {
#pragma unroll
    for (int o = 0; o < 2; ++o)
#pragma unroll
      for (int f = 0; f < 8; ++f)
#pragma unroll
        for (int r = 0; r < 4; ++r) {
          int ch = oc0 + (ocq << 5) + o * 16 + lg * 4 + r;
          if (ch < 100) {
            int row = oy0 + 2 * h + (f >> 2);
            int col = ((f & 3) << 4) + lm;
            int n = row * 64 + col;
            float v = acc[o][f][r] + bia[o][r];
            unsigned short hi = f2bf_rne(v);
            float hif = __builtin_bit_cast(float, ((unsigned int)hi) << 16);
            unsigned short lo = f2bf_rne(v - hif);
            thd_dw[(((size_t)(b << 12) + n) << 7) + ch] =
                (unsigned int)hi | (((unsigned int)lo) << 16);
          }
        }
  }

#pragma unroll
  for (int o = 0; o < 2; ++o)
#pragma unroll
    for (int f = 0; f < 4; ++f)
#pragma unroll
      for (int r = 0; r < 4; ++r) {
        float v = fmaxf(acc[o][f][r], acc[o][f + 4][r]) + bia[o][r];
        float vn = fmaxf(v, __shfl_xor(v, 1));
        int ch = oc0 + (ocq << 5) + o * 16 + lg * 4 + r;
        if (!(lm & 1)) {
          int prow = (oy0 >> 1) + h;
          int mcol = (f << 3) + (lm >> 1);
          int m = (prow << 5) + mcol;
          if (thetaMode) {
            if (ch >= 100 && ch < 200) {
              int c = ch - 100;
              unsigned short hi = f2bf_rne(vn);
              float hif = __builtin_bit_cast(float, ((unsigned int)hi) << 16);
              unsigned short lo = f2bf_rne(vn - hif);
              phd_dw[(((size_t)(b << 10) + m) << 7) + c] =
                  (unsigned int)hi | (((unsigned int)lo) << 16);
            }
          } else {
            int cg = ch - 256;
            if (cg < 200)
              gP[((size_t)(b * 208 + cg) << 10) + m] = f2bf_rne(vn);
          }
        }
      }
}

// ---------------------------------------------------------------------------
// attn_mfma: flash-style attention, dual-bf16 QK^T + online softmax +
// bf16 P@g^T. Block = (b, 64-row n-tile), 8 waves = (4 row-tiles x 2 m-halves)
// LDS: P[64][1024] bf16 XOR-swizzled (128K) + corr[64][32] + stats + inv.
// Swizzle (CONSISTENT on all sides): byte = (row<<11) + ((m*2) ^ ((row&7)<<4))
// ---------------------------------------------------------------------------
__global__ __launch_bounds__(512, 2) void attn_mfma_kernel(
    const unsigned short* __restrict__ thd,  // [8][4096][256]
    const unsigned short* __restrict__ phd,  // [8][1024][256]
    const unsigned short* __restrict__ gP,   // [8][208][1024]
    float* __restrict__ out) {               // [8][200][4096]
  __shared__ __align__(16) char sm[140800];
  float* corrL = (float*)(sm + 131072);   // [64][32]
  float* statsL = (float*)(sm + 139264);  // [64][2][2]
  float* mFinL = (float*)(sm + 140288);   // [64]
  float* invL = (float*)(sm + 140544);    // [64]

  const int bx = blockIdx.x;
  const int b = bx >> 6;
  const int n0 = (bx & 63) << 6;
  const int t = threadIdx.x;
  const int w = t >> 6;
  const int l = t & 63;
  const int lm = l & 15;
  const int lg = l >> 4;
  const int rowTile = w & 3;
  const int mhalf = w >> 2;
  const int rowB = rowTile * 16 + lg * 4;

  // theta A-frags (16 rows x K=256) + pair-swapped copy, once per wave
  short8 aA[8], aS[8];
  {
    const unsigned short* ap =
        thd + (((size_t)(b << 12) + n0 + rowTile * 16 + lm) << 8) + lg * 8;
#pragma unroll
    for (int kf = 0; kf < 8; ++kf) {
      short8 v = *(const short8*)(ap + kf * 32);
      aA[kf] = v;
      uint4v u = __builtin_bit_cast(uint4v, v);
      u.x = (u.x >> 16) | (u.x << 16);
      u.y = (u.y >> 16) | (u.y << 16);
      u.z = (u.z >> 16) | (u.z << 16);
      u.w = (u.w >> 16) | (u.w << 16);
      aS[kf] = __builtin_bit_cast(short8, u);
    }
  }

  float mRun[4], sRun[4];
#pragma unroll
  for (int r = 0; r < 4; ++r) { mRun[r] = -3.0e38f; sRun[r] = 0.0f; }

  // ---- Phase A + online softmax over this wave's 512-m half
  for (int step = 0; step < 16; ++step) {
    const int m0 = mhalf * 512 + step * 32;
    f32x4 ac0 = (f32x4)0.f, ac1 = (f32x4)0.f;
    const unsigned short* bp0 =
        phd + (((size_t)(b << 10) + m0 + lm) << 8) + lg * 8;
    const unsigned short* bp1 = bp0 + (16 << 8);
#pragma unroll
    for (int kf = 0; kf < 8; ++kf) {
      short8 bv0 = *(const short8*)(bp0 + kf * 32);
      short8 bv1 = *(const short8*)(bp1 + kf * 32);
      ac0 = __builtin_amdgcn_mfma_f32_16x16x32_bf16(aA[kf], bv0, ac0, 0, 0, 0);
      ac1 = __builtin_amdgcn_mfma_f32_16x16x32_bf16(aA[kf], bv1, ac1, 0, 0, 0);
      ac0 = __builtin_amdgcn_mfma_f32_16x16x32_bf16(aS[kf], bv0, ac0, 0, 0, 0);
      ac1 = __builtin_amdgcn_mfma_f32_16x16x32_bf16(aS[kf], bv1, ac1, 0, 0, 0);
    }
    // row stats: lane holds rows rowB..rowB+3 at col lm (x2 m-tiles)
    float tmax[4], pv0[4], pv1[4], csum[4];
#pragma unroll
    for (int r = 0; r < 4; ++r) tmax[r] = fmaxf(ac0[r], ac1[r]);
#pragma unroll
    for (int s = 1; s < 16; s <<= 1)
#pragma unroll
      for (int r = 0; r < 4; ++r) tmax[r] = fmaxf(tmax[r], __shfl_xor(tmax[r], s));
#pragma unroll
    for (int r = 0; r < 4; ++r) {
      float mNew = fmaxf(mRun[r], tmax[r]);
      float scale = __expf(mRun[r] - mNew);
      pv0[r] = __expf(ac0[r] - mNew);
      pv1[r] = __expf(ac1[r] - mNew);
      csum[r] = pv0[r] + pv1[r];
      mRun[r] = mNew;
      sRun[r] *= scale;
    }
#pragma unroll
    for (int s = 1; s < 16; s <<= 1)
#pragma unroll
      for (int r = 0; r < 4; ++r) csum[r] += __shfl_xor(csum[r], s);
#pragma unroll
    for (int r = 0; r < 4; ++r) sRun[r] += csum[r];
    // store P (bf16, swizzled: XOR applied to m-offset only -> in-row)
#pragma unroll
    for (int r = 0; r < 4; ++r) {
      int row = rowB + r;
      int sw = ((row & 7) << 4);
      int byte0 = (row << 11) + ((((m0 + lm) << 1)) ^ sw);
      int byte1 = (row << 11) + ((((m0 + 16 + lm) << 1)) ^ sw);
      *(unsigned short*)(sm + byte0) = f2bf_rne(pv0[r]);
      *(unsigned short*)(sm + byte1) = f2bf_rne(pv1[r]);
    }
    if (lm == 0) {
      int chunkIdx = mhalf * 16 + step;
#pragma unroll
      for (int r = 0; r < 4; ++r) corrL[(rowB + r) * 32 + chunkIdx] = mRun[r];
    }
  }
  if (lm == 0) {
#pragma unroll
    for (int r = 0; r < 4; ++r) {
      statsL[((rowB + r) * 2 + mhalf) * 2 + 0] = mRun[r];
      statsL[((rowB + r) * 2 + mhalf) * 2 + 1] = sRun[r];
    }
  }
  __syncthreads();

  // ---- merge the two m-half stats per row
  if (t < 64) {
    float m0v = statsL[(t * 2 + 0) * 2 + 0];
    float s0v = statsL[(t * 2 + 0) * 2 + 1];
    float m1v = statsL[(t * 2 + 1) * 2 + 0];
    float s1v = statsL[(t * 2 + 1) * 2 + 1];
    float mF = fmaxf(m0v, m1v);
    float sF = s0v * __expf(m0v - mF) + s1v * __expf(m1v - mF);
    mFinL[t] = mF;
    invL[t] = 1.0f / sF;
  }
  __syncthreads();

  // ---- convert m_used -> correction factors
  {
    int idx = t * 4;
#pragma unroll
    for (int i = 0; i < 4; ++i) {
      int row = (idx + i) >> 5;
      corrL[idx + i] = __expf(corrL[idx + i] - mFinL[row]);
    }
  }
  __syncthreads();

  // ---- rescale P by per-chunk corrections (same swizzle as write)
  {
    int row = t >> 3;
    int mb = (t & 7) << 7;
    int sw = ((row & 7) << 4);
    for (int j = 0; j < 16; ++j) {
      int m = mb + j * 8;
      int byte = (row << 11) + (((m << 1)) ^ sw);
      float corr = corrL[row * 32 + (m >> 5)];
      short8 pv8 = *(short8*)(sm + byte);
      short8 ov;
#pragma unroll
      for (int e = 0; e < 8; ++e) {
        unsigned short us = (unsigned short)pv8[e];
        float f = __builtin_bit_cast(float, ((unsigned int)us) << 16);
        ov[e] = (short)f2bf_rne(f * corr);
      }
      *(short8*)(sm + byte) = ov;
    }
  }
  __syncthreads();

  // ---- Phase C: out[n][c] = invS[n] * sum_m P[n][m] g[c][m]
  const int nct = mhalf ? 6 : 7;
  const int ct0 = mhalf ? 7 : 0;
  f32x4 oacc[7];
#pragma unroll
  for (int i = 0; i < 7; ++i) oacc[i] = (f32x4)0.f;

  const int rowA = rowTile * 16 + lm;
  const int swA = ((rowA & 7) << 4);
  const int rowABase = (rowA << 11);

  for (int ks = 0; ks < 32; ++ks) {
    short8 ap = *(const short8*)(
        sm + rowABase + ((((ks * 32 + lg * 8) << 1)) ^ swA));
    const unsigned short* gbase =
        gP + ((size_t)(b * 208) << 10) + ks * 32 + lg * 8;
#pragma unroll
    for (int i = 0; i < 7; ++i) {
      if (i < nct) {
        int c = (ct0 + i) * 16 + lm;
        short8 gv = *(const short8*)(gbase + ((size_t)c << 10));
        oacc[i] = __builtin_amdgcn_mfma_f32_16x16x32_bf16(ap, gv, oacc[i], 0, 0, 0);
      }
    }
  }
  {
    float inv[4];
#pragma unroll
    for (int r = 0; r < 4; ++r) inv[r] = invL[rowB + r];
#pragma unroll
    for (int i = 0; i < 7; ++i) {
      if (i < nct) {
        int c = (ct0 + i) * 16 + lm;
        if (c < 200) {
          f32x4 v;
#pragma unroll
          for (int r = 0; r < 4; ++r) v[r] = oacc[i][r] * inv[r];
          *(f32x4*)(out + (((size_t)(b * 200 + c)) << 12) + n0 + rowB) = v;
        }
      }
    }
  }
}

// ---------------------------------------------------------------------------
extern "C" void kernel_launch(void* const* d_in, const int* in_sizes, int n_in,
                              void* d_out, int out_size, void* d_ws,
                              size_t ws_size, hipStream_t stream) {
  const float* x  = (const float*)d_in[0];
  const float* tw = (const float*)d_in[1];
  const float* tb = (const float*)d_in[2];
  const float* pw = (const float*)d_in[3];
  const float* pb = (const float*)d_in[4];
  const float* gw = (const float*)d_in[5];
  const float* gb = (const float*)d_in[6];
  float* out = (float*)d_out;

  unsigned short* ws_us = (unsigned short*)d_ws;
  unsigned short* thd = ws_us;               // 8*4096*256     = 8,388,608 us
  unsigned short* phd = ws_us + 8388608;     // 8*1024*256     = 2,097,152
  unsigned short* gP  = ws_us + 10485760;    // 8*208*1024     = 1,703,936
  unsigned short* xTi = ws_us + 12189696;    // 8*70*70*128    = 5,017,600
  unsigned short* wTi = ws_us + 17207296;    // 49*512*128     = 3,211,264
  float* biasPad = (float*)(ws_us + 20418560);  // 512 f (~40.8 MB total)

  prep_x<<<560, 256, 0, stream>>>(x, (unsigned int*)xTi);
  prep_w<<<6272, 256, 0, stream>>>(tw, pw, gw, (unsigned int*)wTi);
  prep_bias<<<2, 256, 0, stream>>>(tb, pb, gb, biasPad);
  zero_pads<<<4608, 256, 0, stream>>>((unsigned int*)thd, (unsigned int*)phd,
                                      (unsigned int*)gP);

  convmfma_kernel<<<dim3(128, 8), 256, 0, stream>>>(
      xTi, wTi, biasPad, (unsigned int*)thd, (unsigned int*)phd, gP);
  attn_mfma_kernel<<<512, 512, 0, stream>>>(thd, phd, gP, out);
}